// Round 1
// baseline (145.424 us; speedup 1.0000x reference)
//
#include <hip/hip_runtime.h>
#include <hip/hip_bf16.h>
#include <math.h>

#define NUM_EMB 1024
#define DIM 256
#define ROWS 16384            // 8*2048
#define NCHUNK 4
#define NPERCHUNK (NUM_EMB / NCHUNK)   // 256
#define NUMEL 4194304.0f      // 8*2048*256

typedef __attribute__((ext_vector_type(8))) short bf16x8;
typedef __attribute__((ext_vector_type(4))) float f32x4;

// f32 -> bf16 round-to-nearest-even (bit pattern)
__device__ __forceinline__ unsigned short f2bf(float f) {
    unsigned int u = __float_as_uint(f);
    u = (u + 0x7FFFu + ((u >> 16) & 1u)) >> 16;
    return (unsigned short)u;
}

// ws layout (bytes):
//   Ebf  : [0,       524288)   bf16 codebook [1024][256]
//   esq  : [524288,  528384)   f32 [1024]
//   pval : [528384,  790528)   f32 [16384][4]  per-chunk best value
//   pidx : [790528, 1052672)   int [16384][4]  per-chunk best index
//   bsum : [1052672,1069056)   f32 [4096]      per-block loss partials

// ---- k0: codebook f32->bf16 + e_sq ------------------------------------
__global__ __launch_bounds__(256) void k0_convert(
        const float* __restrict__ E, unsigned short* __restrict__ Ebf,
        float* __restrict__ esq) {
    int wid  = threadIdx.x >> 6;
    int lane = threadIdx.x & 63;
    int row  = blockIdx.x * 4 + wid;          // 0..1023
    const float4 v = *(const float4*)(E + row * DIM + lane * 4);
    ushort4 o;
    o.x = f2bf(v.x); o.y = f2bf(v.y); o.z = f2bf(v.z); o.w = f2bf(v.w);
    *(ushort4*)(Ebf + row * DIM + lane * 4) = o;
    float s = v.x * v.x + v.y * v.y + v.z * v.z + v.w * v.w;
    #pragma unroll
    for (int m = 32; m >= 1; m >>= 1) s += __shfl_xor(s, m);
    if (lane == 0) esq[row] = s;
}

// ---- k1: argmin over codebook via bf16 MFMA ---------------------------
// wave -> 16 rows of X, one 256-wide N chunk. 4 waves/block share rows.
__global__ __launch_bounds__(256) void k1_argmin(
        const float* __restrict__ X, const unsigned short* __restrict__ Ebf,
        const float* __restrict__ esq,
        float* __restrict__ pval, int* __restrict__ pidx) {
    int wid   = threadIdx.x >> 6;
    int lane  = threadIdx.x & 63;
    int gw    = blockIdx.x * 4 + wid;
    int chunk = gw & (NCHUNK - 1);
    int mtile = gw >> 2;
    int m0    = mtile * 16;
    int arow  = m0 + (lane & 15);
    int kbase = (lane >> 4) * 8;

    // preload A fragments: X rows m0..m0+15, K=256 -> 8 frags of bf16x8
    bf16x8 a[8];
    #pragma unroll
    for (int kc = 0; kc < 8; ++kc) {
        const float* p = X + arow * DIM + kc * 32 + kbase;
        float4 v0 = *(const float4*)p;
        float4 v1 = *(const float4*)(p + 4);
        bf16x8 t;
        t[0] = f2bf(v0.x); t[1] = f2bf(v0.y); t[2] = f2bf(v0.z); t[3] = f2bf(v0.w);
        t[4] = f2bf(v1.x); t[5] = f2bf(v1.y); t[6] = f2bf(v1.z); t[7] = f2bf(v1.w);
        a[kc] = t;
    }

    float bv[4] = {INFINITY, INFINITY, INFINITY, INFINITY};
    int   bi[4] = {0, 0, 0, 0};
    int n_start = chunk * NPERCHUNK;

    for (int nt = 0; nt < NPERCHUNK / 16; ++nt) {
        int brow = n_start + nt * 16 + (lane & 15);
        const unsigned short* bp = Ebf + brow * DIM + kbase;
        f32x4 acc = {0.f, 0.f, 0.f, 0.f};
        #pragma unroll
        for (int kc = 0; kc < 8; ++kc) {
            bf16x8 b = *(const bf16x8*)(bp + kc * 32);
            acc = __builtin_amdgcn_mfma_f32_16x16x32_bf16(a[kc], b, acc, 0, 0, 0);
        }
        float es = esq[brow];
        #pragma unroll
        for (int r = 0; r < 4; ++r) {
            float val = es - 2.0f * acc[r];   // = dist - ||x||^2 (row-const)
            if (val < bv[r]) { bv[r] = val; bi[r] = brow; }
        }
    }

    // reduce across the 16 lanes of each row-group (masks 1,2,4,8)
    #pragma unroll
    for (int m = 1; m <= 8; m <<= 1) {
        #pragma unroll
        for (int r = 0; r < 4; ++r) {
            float ov = __shfl_xor(bv[r], m);
            int   oi = __shfl_xor(bi[r], m);
            if (ov < bv[r] || (ov == bv[r] && oi < bi[r])) { bv[r] = ov; bi[r] = oi; }
        }
    }
    if ((lane & 15) == 0) {
        int g = lane >> 4;
        #pragma unroll
        for (int r = 0; r < 4; ++r) {
            int row = m0 + g * 4 + r;        // C/D: row=(lane>>4)*4+reg
            pval[row * NCHUNK + chunk] = bv[r];
            pidx[row * NCHUNK + chunk] = bi[r];
        }
    }
}

// ---- k2: final argmin across chunks + gather + loss partials ----------
__global__ __launch_bounds__(256) void k2_gather(
        const float* __restrict__ X, const float* __restrict__ E,
        const float* __restrict__ pval, const int* __restrict__ pidx,
        float* __restrict__ outq, float* __restrict__ bsum) {
    __shared__ float ls[4];
    int wid  = threadIdx.x >> 6;
    int lane = threadIdx.x & 63;
    int row  = blockIdx.x * 4 + wid;

    float v = INFINITY; int i = 0;
    if (lane < NCHUNK) { v = pval[row * NCHUNK + lane]; i = pidx[row * NCHUNK + lane]; }
    #pragma unroll
    for (int m = 1; m <= 2; m <<= 1) {
        float ov = __shfl_xor(v, m);
        int   oi = __shfl_xor(i, m);
        if (ov < v || (ov == v && oi < i)) { v = ov; i = oi; }
    }
    int idx = __shfl(i, 0);

    float s = 0.f;
    #pragma unroll
    for (int j = 0; j < 4; ++j) {
        float e = E[idx * DIM + j * 64 + lane];
        float x = X[row * DIM + j * 64 + lane];
        float d = e - x;
        s += d * d;
        outq[row * DIM + j * 64 + lane] = e;   // exact f32 gather
    }
    #pragma unroll
    for (int m = 32; m >= 1; m >>= 1) s += __shfl_xor(s, m);
    if (lane == 0) ls[wid] = s;
    __syncthreads();
    if (threadIdx.x == 0) bsum[blockIdx.x] = ls[0] + ls[1] + ls[2] + ls[3];
}

// ---- k3: reduce 4096 partials -> loss ---------------------------------
__global__ __launch_bounds__(1024) void k3_loss(
        const float* __restrict__ bsum, float* __restrict__ out) {
    __shared__ float ls[16];
    int t = threadIdx.x;
    float s = bsum[t] + bsum[t + 1024] + bsum[t + 2048] + bsum[t + 3072];
    #pragma unroll
    for (int m = 32; m >= 1; m >>= 1) s += __shfl_xor(s, m);
    int wid = t >> 6, lane = t & 63;
    if (lane == 0) ls[wid] = s;
    __syncthreads();
    if (wid == 0) {
        float v = (lane < 16) ? ls[lane] : 0.f;
        #pragma unroll
        for (int m = 8; m >= 1; m >>= 1) v += __shfl_xor(v, m);
        if (lane == 0) out[0] = 1.25f * v * (1.0f / NUMEL);
    }
}

extern "C" void kernel_launch(void* const* d_in, const int* in_sizes, int n_in,
                              void* d_out, int out_size, void* d_ws, size_t ws_size,
                              hipStream_t stream) {
    const float* X = (const float*)d_in[0];   // [8,2048,256] f32
    const float* E = (const float*)d_in[1];   // [1024,256]   f32
    float* out = (float*)d_out;               // [1 + 4194304] f32
    char* ws = (char*)d_ws;

    unsigned short* Ebf = (unsigned short*)ws;
    float* esq  = (float*)(ws + 524288);
    float* pval = (float*)(ws + 528384);
    int*   pidx = (int*)(ws + 790528);
    float* bsum = (float*)(ws + 1052672);

    k0_convert<<<NUM_EMB / 4, 256, 0, stream>>>(E, Ebf, esq);
    k1_argmin<<<(ROWS / 16) * NCHUNK / 4, 256, 0, stream>>>(X, Ebf, esq, pval, pidx);
    k2_gather<<<ROWS / 4, 256, 0, stream>>>(X, E, pval, pidx, out + 1, bsum);
    k3_loss<<<1, 1024, 0, stream>>>(bsum, out);
}

// Round 2
// 107.811 us; speedup vs baseline: 1.3489x; 1.3489x over previous
//
#include <hip/hip_runtime.h>
#include <math.h>

#define DIM 256
#define NUM_EMB 1024
#define ROWS 16384
#define NUMEL 4194304.0f   // 8*2048*256

typedef __attribute__((ext_vector_type(8))) short bf16x8;
typedef __attribute__((ext_vector_type(4))) float f32x4;

// f32 -> bf16 round-to-nearest-even (bit pattern)
__device__ __forceinline__ unsigned short f2bf(float f) {
    unsigned int u = __float_as_uint(f);
    u = (u + 0x7FFFu + ((u >> 16) & 1u)) >> 16;
    return (unsigned short)u;
}

// ws layout (bytes):
//   Ebf  : [0,      524288)  bf16 codebook in FRAGMENT-LINEAR order:
//          for subtile t(=row/16), kc(=dim/32): 1024B block; lane l=16g+r holds
//          row t*16+r, dims [kc*32+8g, +8) at ushort offset (t*8+kc)*512 + l*8
//   esq  : [524288, 528384)  f32 [1024] codebook row norms (exact f32)
//   bsum : [528384, 530432)  f32 [512]  per-block loss partials

// ---- k0: codebook f32->bf16 (fragment-linear) + e_sq ------------------
__global__ __launch_bounds__(256) void k0_convert(
        const float* __restrict__ E, unsigned short* __restrict__ Ebf,
        float* __restrict__ esq) {
    int tid = blockIdx.x * 256 + threadIdx.x;   // 0..32767, 8 dims each
    int e  = tid >> 5;                          // codebook row
    int d0 = (tid & 31) * 8;                    // first dim
    const float* p = E + e * DIM + d0;
    float4 v0 = *(const float4*)p;
    float4 v1 = *(const float4*)(p + 4);
    int t = e >> 4, r = e & 15, kc = d0 >> 5, g = (d0 >> 3) & 3;
    bf16x8 o;
    o[0] = f2bf(v0.x); o[1] = f2bf(v0.y); o[2] = f2bf(v0.z); o[3] = f2bf(v0.w);
    o[4] = f2bf(v1.x); o[5] = f2bf(v1.y); o[6] = f2bf(v1.z); o[7] = f2bf(v1.w);
    *(bf16x8*)(Ebf + (t * 8 + kc) * 512 + (g * 16 + r) * 8) = o;
    float s = v0.x*v0.x + v0.y*v0.y + v0.z*v0.z + v0.w*v0.w
            + v1.x*v1.x + v1.y*v1.y + v1.z*v1.z + v1.w*v1.w;
    #pragma unroll
    for (int m = 1; m <= 16; m <<= 1) s += __shfl_xor(s, m);
    if ((threadIdx.x & 31) == 0) esq[e] = s;
}

// ---- k1: fused argmin + gather + loss partial -------------------------
// One block = 512 threads = 8 waves = 8 codebook chunks x same 32 X-rows.
__global__ __launch_bounds__(512) void k1_main(
        const float* __restrict__ X, const unsigned short* __restrict__ Ebf,
        const float* __restrict__ esq, const float* __restrict__ E,
        float* __restrict__ outq, float* __restrict__ bsum) {
    __shared__ float sval[8][32];
    __shared__ int   sidx[8][32];
    __shared__ float sxsq[32];
    __shared__ float sloss[32];

    int tid  = threadIdx.x;
    int wid  = tid >> 6;
    int lane = tid & 63;
    int r15  = lane & 15;
    int g    = lane >> 4;
    int m0   = blockIdx.x * 32;

    // ---- A fragments (X rows m0..m0+31) + exact f32 row norms ----
    bf16x8 a[2][8];
    float xs0 = 0.f, xs1 = 0.f;
    #pragma unroll
    for (int mt = 0; mt < 2; ++mt) {
        const float* rp = X + (m0 + mt * 16 + r15) * DIM + g * 8;
        float s = 0.f;
        #pragma unroll
        for (int kc = 0; kc < 8; ++kc) {
            float4 v0 = *(const float4*)(rp + kc * 32);
            float4 v1 = *(const float4*)(rp + kc * 32 + 4);
            bf16x8 t;
            t[0] = f2bf(v0.x); t[1] = f2bf(v0.y); t[2] = f2bf(v0.z); t[3] = f2bf(v0.w);
            t[4] = f2bf(v1.x); t[5] = f2bf(v1.y); t[6] = f2bf(v1.z); t[7] = f2bf(v1.w);
            a[mt][kc] = t;
            s += v0.x*v0.x + v0.y*v0.y + v0.z*v0.z + v0.w*v0.w
               + v1.x*v1.x + v1.y*v1.y + v1.z*v1.z + v1.w*v1.w;
        }
        if (mt == 0) xs0 = s; else xs1 = s;
    }
    xs0 += __shfl_xor(xs0, 16); xs0 += __shfl_xor(xs0, 32);
    xs1 += __shfl_xor(xs1, 16); xs1 += __shfl_xor(xs1, 32);
    if (wid == 0 && lane < 16) { sxsq[lane] = xs0; sxsq[16 + lane] = xs1; }

    // ---- stream this wave's 128 codebook rows (8 subtiles), coalesced ----
    int tbase = wid * 8;
    const unsigned short* EB = Ebf + tbase * 4096;   // (t*8+kc)*512 ushorts
    float bv[2][4] = {{INFINITY,INFINITY,INFINITY,INFINITY},
                      {INFINITY,INFINITY,INFINITY,INFINITY}};
    int   bi[2][4] = {{0,0,0,0},{0,0,0,0}};

    bf16x8 bufA[8], bufB[8];
    #pragma unroll
    for (int kc = 0; kc < 8; ++kc)
        bufA[kc] = *(const bf16x8*)(EB + kc * 512 + lane * 8);

    #pragma unroll
    for (int ns = 0; ns < 8; ++ns) {
        const bf16x8* bc = (ns & 1) ? bufB : bufA;
        bf16x8*       bn = (ns & 1) ? bufA : bufB;
        if (ns < 7) {
            const unsigned short* src = EB + (ns + 1) * 4096;
            #pragma unroll
            for (int kc = 0; kc < 8; ++kc)
                bn[kc] = *(const bf16x8*)(src + kc * 512 + lane * 8);
        }
        float es = esq[(tbase + ns) * 16 + r15];
        f32x4 acc0 = {0.f,0.f,0.f,0.f}, acc1 = {0.f,0.f,0.f,0.f};
        #pragma unroll
        for (int kc = 0; kc < 8; ++kc) {
            acc0 = __builtin_amdgcn_mfma_f32_16x16x32_bf16(a[0][kc], bc[kc], acc0, 0, 0, 0);
            acc1 = __builtin_amdgcn_mfma_f32_16x16x32_bf16(a[1][kc], bc[kc], acc1, 0, 0, 0);
        }
        int brow = (tbase + ns) * 16 + r15;
        #pragma unroll
        for (int r = 0; r < 4; ++r) {
            float v0 = es - 2.f * acc0[r];
            if (v0 < bv[0][r]) { bv[0][r] = v0; bi[0][r] = brow; }
            float v1 = es - 2.f * acc1[r];
            if (v1 < bv[1][r]) { bv[1][r] = v1; bi[1][r] = brow; }
        }
    }

    // ---- per-wave argmin across the 16 lanes of each row-group ----
    #pragma unroll
    for (int m = 1; m <= 8; m <<= 1) {
        #pragma unroll
        for (int mt = 0; mt < 2; ++mt)
            #pragma unroll
            for (int r = 0; r < 4; ++r) {
                float ov = __shfl_xor(bv[mt][r], m);
                int   oi = __shfl_xor(bi[mt][r], m);
                if (ov < bv[mt][r] || (ov == bv[mt][r] && oi < bi[mt][r])) {
                    bv[mt][r] = ov; bi[mt][r] = oi;
                }
            }
    }
    if (r15 == 0) {
        #pragma unroll
        for (int mt = 0; mt < 2; ++mt)
            #pragma unroll
            for (int r = 0; r < 4; ++r) {
                int rl = mt * 16 + g * 4 + r;   // C/D: row=(lane>>4)*4+reg
                sval[wid][rl] = bv[mt][r];
                sidx[wid][rl] = bi[mt][r];
            }
    }
    __syncthreads();

    // ---- cross-chunk argmin (threads 0..255), loss per row ----
    if (tid < 256) {
        int rl = tid >> 3, c = tid & 7;
        float v = sval[c][rl];
        int   i = sidx[c][rl];
        #pragma unroll
        for (int m = 1; m <= 4; m <<= 1) {
            float ov = __shfl_xor(v, m);
            int   oi = __shfl_xor(i, m);
            if (ov < v || (ov == v && oi < i)) { v = ov; i = oi; }
        }
        if (c == 0) {
            sidx[0][rl]  = i;                 // final index broadcast slot
            sloss[rl]    = sxsq[rl] + v;      // ||x-e||^2 (bf16-dot precision)
        }
    }
    __syncthreads();

    // ---- loss partial (wave 0) ----
    if (tid < 32) {
        float l = sloss[tid];
        #pragma unroll
        for (int m = 1; m <= 16; m <<= 1) l += __shfl_xor(l, m);
        if (tid == 0) bsum[blockIdx.x] = l;
    }

    // ---- gather E[idx] (exact f32) and write quantized, coalesced ----
    #pragma unroll
    for (int p = 0; p < 16; ++p) {
        int elem = p * 512 + tid;
        int rl = elem >> 8, d = elem & 255;
        int idx = sidx[0][rl];
        outq[(m0 + rl) * DIM + d] = E[idx * DIM + d];
    }
}

// ---- k3: reduce 512 partials -> loss ----------------------------------
__global__ __launch_bounds__(512) void k3_loss(
        const float* __restrict__ bsum, float* __restrict__ out) {
    __shared__ float ls[8];
    int tid = threadIdx.x;
    float s = bsum[tid];
    #pragma unroll
    for (int m = 1; m <= 32; m <<= 1) s += __shfl_xor(s, m);
    if ((tid & 63) == 0) ls[tid >> 6] = s;
    __syncthreads();
    if (tid < 8) {
        float v = ls[tid];
        #pragma unroll
        for (int m = 1; m <= 4; m <<= 1) v += __shfl_xor(v, m);
        if (tid == 0) out[0] = 1.25f * v * (1.0f / NUMEL);
    }
}

extern "C" void kernel_launch(void* const* d_in, const int* in_sizes, int n_in,
                              void* d_out, int out_size, void* d_ws, size_t ws_size,
                              hipStream_t stream) {
    const float* X = (const float*)d_in[0];   // [8,2048,256] f32
    const float* E = (const float*)d_in[1];   // [1024,256]   f32
    float* out = (float*)d_out;               // [1 + 4194304] f32
    char* ws = (char*)d_ws;

    unsigned short* Ebf = (unsigned short*)ws;
    float* esq  = (float*)(ws + 524288);
    float* bsum = (float*)(ws + 528384);

    k0_convert<<<128, 256, 0, stream>>>(E, Ebf, esq);
    k1_main<<<ROWS / 32, 512, 0, stream>>>(X, Ebf, esq, E, out + 1, bsum);
    k3_loss<<<1, 512, 0, stream>>>(bsum, out);
}

// Round 3
// 97.749 us; speedup vs baseline: 1.4877x; 1.1029x over previous
//
#include <hip/hip_runtime.h>
#include <math.h>

#define DIM 256
#define NUM_EMB 1024
#define ROWS 16384
#define NUMEL 4194304.0f   // 8*2048*256

typedef __attribute__((ext_vector_type(8))) short bf16x8;
typedef __attribute__((ext_vector_type(4))) float f32x4;

// f32 -> bf16 round-to-nearest-even (bit pattern)
__device__ __forceinline__ unsigned short f2bf(float f) {
    unsigned int u = __float_as_uint(f);
    u = (u + 0x7FFFu + ((u >> 16) & 1u)) >> 16;
    return (unsigned short)u;
}

// ws layout (bytes):
//   Ebf : [0,       524288)   bf16 codebook, fragment-linear:
//         subtile t=row/16, kc=dim/32 -> 1024B block; lane l=16g+r holds
//         row t*16+r, dims [kc*32+8g,+8) at ushort off (t*8+kc)*512 + l*8
//   Xbf : [524288,  8912896)  bf16 inputs, same layout, t=row/16 in [0,1024)
//   esq : [8912896, 8916992)  f32 [1024]  codebook row norms (exact)
//   xsq : [8916992, 8982528)  f32 [16384] input row norms (exact)
//   bsum: [8982528, 8984576)  f32 [512]   per-block loss partials

// ---- kprep: f32 rows -> fragment-linear bf16 + exact row sq-norms -----
// one wave per 16-row subtile; writes perfectly coalesced (1KB/frag).
__global__ __launch_bounds__(256) void kprep(
        const float* __restrict__ src, unsigned short* __restrict__ dst,
        float* __restrict__ sq) {
    int t = blockIdx.x * 4 + (threadIdx.x >> 6);
    int l = threadIdx.x & 63;
    int r = l & 15, g = l >> 4;
    const float* rp = src + (t * 16 + r) * DIM + g * 8;
    float s = 0.f;
    #pragma unroll
    for (int kc = 0; kc < 8; ++kc) {
        float4 v0 = *(const float4*)(rp + kc * 32);
        float4 v1 = *(const float4*)(rp + kc * 32 + 4);
        bf16x8 o;
        o[0] = f2bf(v0.x); o[1] = f2bf(v0.y); o[2] = f2bf(v0.z); o[3] = f2bf(v0.w);
        o[4] = f2bf(v1.x); o[5] = f2bf(v1.y); o[6] = f2bf(v1.z); o[7] = f2bf(v1.w);
        *(bf16x8*)(dst + (t * 8 + kc) * 512 + l * 8) = o;
        s += v0.x*v0.x + v0.y*v0.y + v0.z*v0.z + v0.w*v0.w
           + v1.x*v1.x + v1.y*v1.y + v1.z*v1.z + v1.w*v1.w;
    }
    s += __shfl_xor(s, 16);
    s += __shfl_xor(s, 32);
    if (g == 0) sq[t * 16 + r] = s;
}

// ---- k1: fused argmin + gather + loss partial -------------------------
// 256 threads = 4 waves; wave wid streams codebook rows [wid*256,+256)
// against the block's 32 X-rows. No address-taken locals (scratch hazard).
__global__ __launch_bounds__(256) void k1_main(
        const unsigned short* __restrict__ Xbf,
        const unsigned short* __restrict__ Ebf,
        const float* __restrict__ esq, const float* __restrict__ xsq,
        const float* __restrict__ E,
        float* __restrict__ outq, float* __restrict__ bsum) {
    __shared__ float sval[4][32];
    __shared__ int   sidx[4][32];
    __shared__ float sloss[32];

    int tid  = threadIdx.x;
    int wid  = tid >> 6;
    int lane = tid & 63;
    int r15  = lane & 15;
    int g    = lane >> 4;
    int m0   = blockIdx.x * 32;

    // A fragments: X rows m0..m0+31, coalesced fragment-linear loads
    bf16x8 a0[8], a1[8];
    #pragma unroll
    for (int kc = 0; kc < 8; ++kc) {
        a0[kc] = *(const bf16x8*)(Xbf + ((blockIdx.x * 2 + 0) * 8 + kc) * 512 + lane * 8);
        a1[kc] = *(const bf16x8*)(Xbf + ((blockIdx.x * 2 + 1) * 8 + kc) * 512 + lane * 8);
    }

    float bv0[4] = {INFINITY, INFINITY, INFINITY, INFINITY};
    float bv1[4] = {INFINITY, INFINITY, INFINITY, INFINITY};
    int   bi0[4] = {0, 0, 0, 0};
    int   bi1[4] = {0, 0, 0, 0};

    #pragma unroll
    for (int ns = 0; ns < 16; ++ns) {
        int te = wid * 16 + ns;                       // codebook subtile
        const unsigned short* eb = Ebf + te * 4096 + lane * 8;
        bf16x8 b[8];
        #pragma unroll
        for (int kc = 0; kc < 8; ++kc)
            b[kc] = *(const bf16x8*)(eb + kc * 512);
        float es = esq[te * 16 + r15];
        f32x4 acc0 = {0.f, 0.f, 0.f, 0.f};
        f32x4 acc1 = {0.f, 0.f, 0.f, 0.f};
        #pragma unroll
        for (int kc = 0; kc < 8; ++kc) {
            acc0 = __builtin_amdgcn_mfma_f32_16x16x32_bf16(a0[kc], b[kc], acc0, 0, 0, 0);
            acc1 = __builtin_amdgcn_mfma_f32_16x16x32_bf16(a1[kc], b[kc], acc1, 0, 0, 0);
        }
        int brow = te * 16 + r15;
        #pragma unroll
        for (int r = 0; r < 4; ++r) {
            float v0 = es - 2.f * acc0[r];
            if (v0 < bv0[r]) { bv0[r] = v0; bi0[r] = brow; }
            float v1 = es - 2.f * acc1[r];
            if (v1 < bv1[r]) { bv1[r] = v1; bi1[r] = brow; }
        }
    }

    // per-wave argmin across the 16 lanes of each row-group
    #pragma unroll
    for (int m = 1; m <= 8; m <<= 1) {
        #pragma unroll
        for (int r = 0; r < 4; ++r) {
            float ov; int oi;
            ov = __shfl_xor(bv0[r], m); oi = __shfl_xor(bi0[r], m);
            if (ov < bv0[r] || (ov == bv0[r] && oi < bi0[r])) { bv0[r] = ov; bi0[r] = oi; }
            ov = __shfl_xor(bv1[r], m); oi = __shfl_xor(bi1[r], m);
            if (ov < bv1[r] || (ov == bv1[r] && oi < bi1[r])) { bv1[r] = ov; bi1[r] = oi; }
        }
    }
    if (r15 == 0) {
        #pragma unroll
        for (int r = 0; r < 4; ++r) {
            sval[wid][g * 4 + r]      = bv0[r];   // C/D: row=(lane>>4)*4+reg
            sidx[wid][g * 4 + r]      = bi0[r];
            sval[wid][16 + g * 4 + r] = bv1[r];
            sidx[wid][16 + g * 4 + r] = bi1[r];
        }
    }
    __syncthreads();

    // cross-chunk argmin (4 chunks), loss per row
    if (tid < 128) {
        int rl = tid >> 2, c = tid & 3;
        float v = sval[c][rl];
        int   i = sidx[c][rl];
        #pragma unroll
        for (int m = 1; m <= 2; m <<= 1) {
            float ov = __shfl_xor(v, m);
            int   oi = __shfl_xor(i, m);
            if (ov < v || (ov == v && oi < i)) { v = ov; i = oi; }
        }
        if (c == 0) {
            sidx[0][rl] = i;                      // final index broadcast
            sloss[rl]   = xsq[m0 + rl] + v;       // ||x-e||^2 (bf16-dot prec)
        }
    }
    __syncthreads();

    // loss partial (wave 0)
    if (tid < 32) {
        float l = sloss[tid];
        #pragma unroll
        for (int m = 1; m <= 16; m <<= 1) l += __shfl_xor(l, m);
        if (tid == 0) bsum[blockIdx.x] = l;
    }

    // gather E[idx] (exact f32), one coalesced row per iteration
    #pragma unroll 4
    for (int p = 0; p < 32; ++p) {
        int idx = sidx[0][p];
        outq[(m0 + p) * DIM + tid] = E[idx * DIM + tid];
    }
}

// ---- k3: reduce 512 partials -> loss ----------------------------------
__global__ __launch_bounds__(512) void k3_loss(
        const float* __restrict__ bsum, float* __restrict__ out) {
    __shared__ float ls[8];
    int tid = threadIdx.x;
    float s = bsum[tid];
    #pragma unroll
    for (int m = 1; m <= 32; m <<= 1) s += __shfl_xor(s, m);
    if ((tid & 63) == 0) ls[tid >> 6] = s;
    __syncthreads();
    if (tid < 8) {
        float v = ls[tid];
        #pragma unroll
        for (int m = 1; m <= 4; m <<= 1) v += __shfl_xor(v, m);
        if (tid == 0) out[0] = 1.25f * v * (1.0f / NUMEL);
    }
}

extern "C" void kernel_launch(void* const* d_in, const int* in_sizes, int n_in,
                              void* d_out, int out_size, void* d_ws, size_t ws_size,
                              hipStream_t stream) {
    const float* X = (const float*)d_in[0];   // [8,2048,256] f32
    const float* E = (const float*)d_in[1];   // [1024,256]   f32
    float* out = (float*)d_out;               // [1 + 4194304] f32
    char* ws = (char*)d_ws;

    unsigned short* Ebf = (unsigned short*)ws;
    unsigned short* Xbf = (unsigned short*)(ws + 524288);
    float* esq  = (float*)(ws + 8912896);
    float* xsq  = (float*)(ws + 8916992);
    float* bsum = (float*)(ws + 8982528);

    kprep<<<NUM_EMB / 64, 256, 0, stream>>>(E, Ebf, esq);   // 16 blocks
    kprep<<<ROWS / 64, 256, 0, stream>>>(X, Xbf, xsq);      // 256 blocks
    k1_main<<<ROWS / 32, 256, 0, stream>>>(Xbf, Ebf, esq, xsq, E, out + 1, bsum);
    k3_loss<<<1, 512, 0, stream>>>(bsum, out);
}